// Round 5
// baseline (1399.908 us; speedup 1.0000x reference)
//
#include <hip/hip_runtime.h>

typedef _Float16 f16;
typedef _Float16 f16x2 __attribute__((ext_vector_type(2)));
typedef _Float16 f16x8 __attribute__((ext_vector_type(8)));
typedef float    f32x4 __attribute__((ext_vector_type(4)));
typedef unsigned int u32x4 __attribute__((ext_vector_type(4)));

// ---------- helpers ----------
__device__ __forceinline__ float dot2u(unsigned a, unsigned b, float c){
  return __builtin_amdgcn_fdot2(__builtin_bit_cast(f16x2, a),
                                __builtin_bit_cast(f16x2, b), c, false);
}
__device__ __forceinline__ float sigm(float x){ return 1.0f/(1.0f+__expf(-x)); }
__device__ __forceinline__ float tanh_(float x){
  x = fminf(fmaxf(x, -20.f), 20.f);
  return 1.0f - 2.0f/(__expf(2.0f*x)+1.0f);
}

// manual OCP e4m3fn encode (RNE) — no fp8 builtins needed
__device__ __forceinline__ unsigned char enc_e4m3(float x){
  unsigned bits = __builtin_bit_cast(unsigned, x);
  unsigned s = (bits >> 24) & 0x80u;
  float ax = __builtin_bit_cast(float, bits & 0x7fffffffu);
  if (ax < 9.765625e-4f) return (unsigned char)s;           // < 2^-10 -> 0
  if (ax >= 448.0f) return (unsigned char)(s | 0x7e);
  int e; (void)frexpf(ax, &e);                              // ax = m*2^e, m in [0.5,1)
  int E = e - 1;
  if (E < -6){                                              // subnormal, quantum 2^-9
    int qi = (int)rintf(ldexpf(ax, 9));                     // 0..8
    if (qi >= 8) return (unsigned char)(s | 0x08);
    return (unsigned char)(s | qi);
  }
  int qi = (int)rintf(ldexpf(ax, 3 - E));                   // 8..16
  if (qi >= 16){ E++; qi = 8; if (E > 8) return (unsigned char)(s | 0x7e); }
  return (unsigned char)(s | (unsigned)((E + 7) << 3) | (unsigned)(qi - 8));
}

// ---------- K0: fp32 -> f16 convert (8 elems/thread) ----------
__global__ void k_cvt(const float* __restrict__ src, f16* __restrict__ dst, int n){
  int i = (blockIdx.x*256 + threadIdx.x)*8;
  if (i >= n) return;
  float4 a = *(const float4*)(src + i);
  float4 b = *(const float4*)(src + i + 4);
  f16x8 o;
  o[0]=(f16)a.x; o[1]=(f16)a.y; o[2]=(f16)a.z; o[3]=(f16)a.w;
  o[4]=(f16)b.x; o[5]=(f16)b.y; o[6]=(f16)b.z; o[7]=(f16)b.w;
  *(f16x8*)(dst+i) = o;
}

// ---------- K0c: pack W_hh into fp8 MFMA A-fragments ----------
// Entry idx = dir*32768 + wv*4096 + rt*512 + kt*64 + lane (one 8-byte frag each).
// Lane holds A[row][k] for row = lane&15 (within the 16-row tile), k = kt*32 +
// (lane>>4)*8 + j (j = byte index). Output row n = wv*128 + rt*16 + (lane&15)
// maps to W_hh row n (gate-major). Weights prescaled by 16 into e4m3.
__global__ void k_wpack5(const float* __restrict__ whf, const float* __restrict__ whb,
                         unsigned int* __restrict__ wf){
  int idx = blockIdx.x*256 + threadIdx.x;    // 0..65535
  int lane = idx & 63;
  int kt   = (idx >> 6) & 7;
  int rt   = (idx >> 9) & 7;
  int wv   = (idx >> 12) & 7;
  int dir  = (idx >> 15) & 1;
  const float* w = dir ? whb : whf;
  int n  = wv*128 + rt*16 + (lane & 15);
  int k0 = kt*32 + (lane >> 4)*8;
  const float* row = w + (size_t)n*256 + k0;
  unsigned char by[8];
  #pragma unroll
  for (int j=0;j<8;j++) by[j] = enc_e4m3(row[j] * 16.0f);
  unsigned lo = (unsigned)by[0] | ((unsigned)by[1]<<8) | ((unsigned)by[2]<<16) | ((unsigned)by[3]<<24);
  unsigned hi = (unsigned)by[4] | ((unsigned)by[5]<<8) | ((unsigned)by[6]<<16) | ((unsigned)by[7]<<24);
  wf[(size_t)idx*2]   = lo;
  wf[(size_t)idx*2+1] = hi;
}

// ---------- K1: gx = X(32768x768) @ Wcat(2048x768)^T  (f16 out, fp32 acc MFMA) ----------
__global__ __launch_bounds__(256) void k_gemm(const f16* __restrict__ A,
                                              const f16* __restrict__ Bw,
                                              f16* __restrict__ C){
  __shared__ alignas(16) f16 As[128][64];
  __shared__ alignas(16) f16 Bs[128][64];
  int bid = blockIdx.x;
  int bm = bid >> 4, bn = bid & 15;
  int tid = threadIdx.x;
  int w = tid >> 6, l = tid & 63;
  int wm = w >> 1, wn = w & 1;
  f32x4 acc[4][4] = {};
  int srow = tid >> 3;
  int scol = (tid & 7)*8;
  const f16* Ag = A  + (size_t)(bm*128)*768 + scol;
  const f16* Bg = Bw + (size_t)(bn*128)*768 + scol;
  int fr = l & 15, kg = l >> 4;
  for (int k0 = 0; k0 < 768; k0 += 64){
    #pragma unroll
    for (int q=0;q<4;q++){
      int rr = srow + 32*q;
      u32x4 av = *(const u32x4*)(Ag + rr*768 + k0);
      u32x4 bv = *(const u32x4*)(Bg + rr*768 + k0);
      *(u32x4*)&As[rr][scol] = av;
      *(u32x4*)&Bs[rr][scol] = bv;
    }
    __syncthreads();
    #pragma unroll
    for (int ks=0; ks<2; ks++){
      f16x8 af[4], bf[4];
      #pragma unroll
      for (int mi=0;mi<4;mi++) af[mi] = *(const f16x8*)&As[wm*64+mi*16+fr][ks*32+kg*8];
      #pragma unroll
      for (int ni=0;ni<4;ni++) bf[ni] = *(const f16x8*)&Bs[wn*64+ni*16+fr][ks*32+kg*8];
      #pragma unroll
      for (int mi=0;mi<4;mi++)
        #pragma unroll
        for (int ni=0;ni<4;ni++)
          acc[mi][ni] = __builtin_amdgcn_mfma_f32_16x16x32_f16(af[mi], bf[ni], acc[mi][ni], 0,0,0);
    }
    __syncthreads();
  }
  int fq = l >> 4;
  #pragma unroll
  for (int mi=0;mi<4;mi++)
    #pragma unroll
    for (int ni=0;ni<4;ni++){
      int mrow = bm*128 + wm*64 + mi*16 + fq*4;
      int ncol = bn*128 + wn*64 + ni*16 + fr;
      #pragma unroll
      for (int r=0;r<4;r++)
        C[(size_t)(mrow+r)*2048 + ncol] = (f16)acc[mi][ni][r];
    }
}

// ---------- K2: recurrence via fp8 MFMA. One block per chain; 512 thr = 8 waves ----------
// Wave wv owns gate-output rows [wv*128, wv*128+128) = 8 row-tiles of 16.
// A (weights, e4m3, x16 prescale) stationary in regs/AGPRs: 64 frags (128 regs).
// B = h (e4m3) replicated into all 16 MFMA columns; each lane reads its 8-fp8
// k-slice from a 256B LDS buffer (8 ds_read_b64 per wave-step total).
// D accumulated over 8 k-tiles into 8 C-frags; rows extracted by col-0 lanes
// into pacc; 256 combine threads do gx+bias+nonlinearity and publish h.
__global__ __launch_bounds__(512,2) void k_rnn(const unsigned int* __restrict__ wfrag,
            const f16* __restrict__ gx, const float* __restrict__ bfp,
            const float* __restrict__ bbp, f16* __restrict__ Hc){
  __shared__ alignas(16) float pacc[1024];
  __shared__ alignas(8) unsigned char lh8[2][256];
  int chain = blockIdx.x;
  int b = chain >> 1, dir = chain & 1;
  int tid = threadIdx.x;
  int wv = tid >> 6, lane = tid & 63;
  int klo = (lane >> 4) * 8;
  int u = tid & 255;
  const long* wf = (const long*)wfrag + (size_t)(dir*8 + wv)*4096 + lane;
  long a[64];                                   // a[rt*8+kt]
  #pragma unroll
  for (int i=0;i<64;i++) a[i] = wf[(size_t)i*64];
  const float* bias = dir ? bbp : bfp;
  const f16* gxc = gx + (size_t)(b*512)*2048;
  f16* Hcc = Hc + (size_t)(b*512)*512 + dir*256 + u;
  float bia0=0.f,bia1=0.f,bia2=0.f,bia3=0.f, c=0.f;
  f16 gn0=(f16)0.f, gn1=(f16)0.f, gn2=(f16)0.f, gn3=(f16)0.f;
  if (tid < 256){
    bia0 = bias[u]; bia1 = bias[256+u]; bia2 = bias[512+u]; bia3 = bias[768+u];
    lh8[0][u] = 0;
    int s0 = dir ? 511 : 0;
    const f16* gp = gxc + (size_t)s0*2048 + dir*1024 + u;
    gn0 = gp[0]; gn1 = gp[256]; gn2 = gp[512]; gn3 = gp[768];
  }
  __syncthreads();
  for (int t=0; t<512; t++){
    int cur = t & 1;
    f32x4 ac0={0,0,0,0},ac1={0,0,0,0},ac2={0,0,0,0},ac3={0,0,0,0};
    f32x4 ac4={0,0,0,0},ac5={0,0,0,0},ac6={0,0,0,0},ac7={0,0,0,0};
    #pragma unroll
    for (int kt=0; kt<8; kt++){
      long hb = *(const long*)&lh8[cur][kt*32 + klo];
      ac0 = __builtin_amdgcn_mfma_f32_16x16x32_fp8_fp8(a[0*8+kt], hb, ac0, 0,0,0);
      ac1 = __builtin_amdgcn_mfma_f32_16x16x32_fp8_fp8(a[1*8+kt], hb, ac1, 0,0,0);
      ac2 = __builtin_amdgcn_mfma_f32_16x16x32_fp8_fp8(a[2*8+kt], hb, ac2, 0,0,0);
      ac3 = __builtin_amdgcn_mfma_f32_16x16x32_fp8_fp8(a[3*8+kt], hb, ac3, 0,0,0);
      ac4 = __builtin_amdgcn_mfma_f32_16x16x32_fp8_fp8(a[4*8+kt], hb, ac4, 0,0,0);
      ac5 = __builtin_amdgcn_mfma_f32_16x16x32_fp8_fp8(a[5*8+kt], hb, ac5, 0,0,0);
      ac6 = __builtin_amdgcn_mfma_f32_16x16x32_fp8_fp8(a[6*8+kt], hb, ac6, 0,0,0);
      ac7 = __builtin_amdgcn_mfma_f32_16x16x32_fp8_fp8(a[7*8+kt], hb, ac7, 0,0,0);
    }
    if ((lane & 15) == 0){
      int pb = wv*128 + (lane >> 4)*4;          // row within tile = (lane>>4)*4 + reg
      *(f32x4*)&pacc[pb +   0] = ac0;
      *(f32x4*)&pacc[pb +  16] = ac1;
      *(f32x4*)&pacc[pb +  32] = ac2;
      *(f32x4*)&pacc[pb +  48] = ac3;
      *(f32x4*)&pacc[pb +  64] = ac4;
      *(f32x4*)&pacc[pb +  80] = ac5;
      *(f32x4*)&pacc[pb +  96] = ac6;
      *(f32x4*)&pacc[pb + 112] = ac7;
    }
    __syncthreads();
    if (tid < 256){
      int s = dir ? (511-t) : t;
      float p0 = pacc[      u]*0.0625f + bia0 + (float)gn0;
      float p1 = pacc[256 + u]*0.0625f + bia1 + (float)gn1;
      float p2 = pacc[512 + u]*0.0625f + bia2 + (float)gn2;
      float p3 = pacc[768 + u]*0.0625f + bia3 + (float)gn3;
      int tn = (t < 511) ? t+1 : 511;
      int sn = dir ? (511 - tn) : tn;
      const f16* gp = gxc + (size_t)sn*2048 + dir*1024 + u;
      gn0 = gp[0]; gn1 = gp[256]; gn2 = gp[512]; gn3 = gp[768];
      float ig = sigm(p0), fg = sigm(p1);
      float gg = tanh_(p2), og = sigm(p3);
      c = fg*c + ig*gg;
      float h = og*tanh_(c);
      Hcc[(size_t)s*512] = (f16)h;
      lh8[cur^1][u] = enc_e4m3(h);
    }
    __syncthreads();
  }
}

// ---------- K3: emissions e[m][k] = Hcat[m] . Wproj[k] + b_proj[k]  (wave per row) ----------
__global__ __launch_bounds__(256) void k_emis(const f16* __restrict__ Hc,
                 const f16* __restrict__ Wp, const float* __restrict__ bp,
                 float* __restrict__ e){
  int w = threadIdx.x >> 6, l = threadIdx.x & 63;
  int m = blockIdx.x*4 + w;
  f16x8 hv = *(const f16x8*)(Hc + (size_t)m*512 + l*8);
  u32x4 hu = __builtin_bit_cast(u32x4, hv);
  #pragma unroll
  for (int k=0;k<9;k++){
    f16x8 wv = *(const f16x8*)(Wp + k*512 + l*8);
    u32x4 wu = __builtin_bit_cast(u32x4, wv);
    float p = 0.f;
    #pragma unroll
    for (int q=0;q<4;q++) p = dot2u(hu[q], wu[q], p);
    #pragma unroll
    for (int off=32; off; off>>=1) p += __shfl_xor(p, off);
    if (l == k) e[(size_t)m*9 + k] = p + bp[k];
  }
}

// ---------- K4: CRF negative-llh pieces per batch (1 wave per batch) ----------
__global__ void k_crf(const float* __restrict__ e, const int* __restrict__ tags,
                      const int* __restrict__ mask, const float* __restrict__ st,
                      const float* __restrict__ en, const float* __restrict__ tr,
                      float* __restrict__ llh){
  int b = blockIdx.x;
  int l = threadIdx.x;
  int j = (l < 9) ? l : 0;
  float Tc[9];
  #pragma unroll
  for (int i=0;i<9;i++) Tc[i] = tr[i*9 + j];
  const float* eb = e + (size_t)b*512*9;
  const int* tb = tags + b*512;
  const int* mb = mask + b*512;
  float a = st[j] + eb[j];
  int t0 = tb[0];
  float num = st[t0] + eb[t0];
  int prev = t0;
  int cnt = (mb[0] != 0) ? 1 : 0;
  for (int s=1; s<512; s++){
    float ej = eb[s*9 + j];
    float vi[9];
    #pragma unroll
    for (int i=0;i<9;i++) vi[i] = __shfl(a, i) + Tc[i];
    float mx = vi[0];
    #pragma unroll
    for (int i=1;i<9;i++) mx = fmaxf(mx, vi[i]);
    float ssum = 0.f;
    #pragma unroll
    for (int i=0;i<9;i++) ssum += expf(vi[i]-mx);
    float anew = ej + mx + logf(ssum);
    int mt = mb[s];
    a = (mt != 0) ? anew : a;
    int tg = tb[s];
    num += (float)mt * (tr[prev*9+tg] + eb[s*9+tg]);
    prev = tg;
    cnt += (mt != 0) ? 1 : 0;
  }
  float av[9];
  #pragma unroll
  for (int i=0;i<9;i++) av[i] = __shfl(a, i) + en[i];
  float mx = av[0];
  #pragma unroll
  for (int i=1;i<9;i++) mx = fmaxf(mx, av[i]);
  float ssum = 0.f;
  #pragma unroll
  for (int i=0;i<9;i++) ssum += expf(av[i]-mx);
  float logZ = mx + logf(ssum);
  if (l == 0){
    int lastt = tb[cnt-1];
    llh[b] = (num + en[lastt]) - logZ;
  }
}

// ---------- K5: final reduce ----------
__global__ void k_red(const float* __restrict__ llh, float* __restrict__ out){
  if (threadIdx.x == 0){
    float s = 0.f;
    for (int i=0;i<64;i++) s += llh[i];
    out[0] = -s / 64.0f;
  }
}

extern "C" void kernel_launch(void* const* d_in, const int* in_sizes, int n_in,
                              void* d_out, int out_size, void* d_ws, size_t ws_size,
                              hipStream_t stream){
  const float* emb  = (const float*)d_in[0];
  const int*   tags = (const int*)d_in[1];
  const int*   mask = (const int*)d_in[2];
  const float* wihf = (const float*)d_in[3];
  const float* whhf = (const float*)d_in[4];
  const float* bfp  = (const float*)d_in[5];
  const float* wihb = (const float*)d_in[6];
  const float* whhb = (const float*)d_in[7];
  const float* bbp  = (const float*)d_in[8];
  const float* wprj = (const float*)d_in[9];
  const float* bprj = (const float*)d_in[10];
  const float* st   = (const float*)d_in[11];
  const float* en   = (const float*)d_in[12];
  const float* tr   = (const float*)d_in[13];

  char* ws = (char*)d_ws;
  f16*   Xf    = (f16*)(ws + 0);                 // 50,331,648 B (aliased by Hc later)
  f16*   Wcat  = (f16*)(ws + 50331648);          //  3,145,728 B
  unsigned int* Wpack = (unsigned int*)(ws + 53477376);  // 524,288 B used (1 MB slot)
  f16*   Wpj   = (f16*)(ws + 54525952);          //      9,216 B
  f16*   gx    = (f16*)(ws + 54535168);          // 134,217,728 B
  float* e     = (float*)(ws + 188752896);       //  1,179,648 B
  float* llh   = (float*)(ws + 189932544);       //        256 B
  f16*   Hc    = Xf;   // safe alias: X only read by k_gemm, which precedes k_rnn

  hipLaunchKernelGGL(k_cvt,    dim3(12288), dim3(256), 0, stream, emb,  Xf, 25165824);
  hipLaunchKernelGGL(k_cvt,    dim3(384),   dim3(256), 0, stream, wihf, Wcat,          786432);
  hipLaunchKernelGGL(k_cvt,    dim3(384),   dim3(256), 0, stream, wihb, Wcat + 786432, 786432);
  hipLaunchKernelGGL(k_cvt,    dim3(3),     dim3(256), 0, stream, wprj, Wpj, 4608);
  hipLaunchKernelGGL(k_wpack5, dim3(256),   dim3(256), 0, stream, whhf, whhb, Wpack);
  hipLaunchKernelGGL(k_gemm,   dim3(4096),  dim3(256), 0, stream, Xf, Wcat, gx);
  hipLaunchKernelGGL(k_rnn,    dim3(128),   dim3(512), 0, stream, Wpack, gx, bfp, bbp, Hc);
  hipLaunchKernelGGL(k_emis,   dim3(8192),  dim3(256), 0, stream, Hc, Wpj, bprj, e);
  hipLaunchKernelGGL(k_crf,    dim3(64),    dim3(64),  0, stream, e, tags, mask, st, en, tr, llh);
  hipLaunchKernelGGL(k_red,    dim3(1),     dim3(64),  0, stream, llh, (float*)d_out);
}

// Round 6
// 1369.758 us; speedup vs baseline: 1.0220x; 1.0220x over previous
//
#include <hip/hip_runtime.h>

typedef _Float16 f16;
typedef _Float16 f16x2 __attribute__((ext_vector_type(2)));
typedef _Float16 f16x8 __attribute__((ext_vector_type(8)));
typedef float    f32x4 __attribute__((ext_vector_type(4)));
typedef unsigned int u32x4 __attribute__((ext_vector_type(4)));

// ---------- helpers ----------
__device__ __forceinline__ float dot2u(unsigned a, unsigned b, float c){
  return __builtin_amdgcn_fdot2(__builtin_bit_cast(f16x2, a),
                                __builtin_bit_cast(f16x2, b), c, false);
}
__device__ __forceinline__ float sigm(float x){ return 1.0f/(1.0f+__expf(-x)); }
__device__ __forceinline__ float tanh_(float x){
  x = fminf(fmaxf(x, -20.f), 20.f);
  return 1.0f - 2.0f/(__expf(2.0f*x)+1.0f);
}

// Barrier that does NOT drain vmcnt: in-loop cross-thread traffic is LDS-only,
// so lgkmcnt(0) suffices; global prefetches stay in flight across steps.
// (hipcc's __syncthreads always emits s_waitcnt vmcnt(0) — that drain was the
// structural ~900cyc/step stall in r2-r5.)
__device__ __forceinline__ void bar_lgkm(){
  asm volatile("s_waitcnt lgkmcnt(0)\n\ts_barrier" ::: "memory");
}

// manual OCP e4m3fn encode (RNE) — used in weight-pack prep only
__device__ __forceinline__ unsigned char enc_e4m3(float x){
  unsigned bits = __builtin_bit_cast(unsigned, x);
  unsigned s = (bits >> 24) & 0x80u;
  float ax = __builtin_bit_cast(float, bits & 0x7fffffffu);
  if (ax < 9.765625e-4f) return (unsigned char)s;           // < 2^-10 -> 0
  if (ax >= 448.0f) return (unsigned char)(s | 0x7e);
  int e; (void)frexpf(ax, &e);                              // ax = m*2^e, m in [0.5,1)
  int E = e - 1;
  if (E < -6){                                              // subnormal, quantum 2^-9
    int qi = (int)rintf(ldexpf(ax, 9));                     // 0..8
    if (qi >= 8) return (unsigned char)(s | 0x08);
    return (unsigned char)(s | qi);
  }
  int qi = (int)rintf(ldexpf(ax, 3 - E));                   // 8..16
  if (qi >= 16){ E++; qi = 8; if (E > 8) return (unsigned char)(s | 0x7e); }
  return (unsigned char)(s | (unsigned)((E + 7) << 3) | (unsigned)(qi - 8));
}

__device__ __forceinline__ unsigned char enc_e4m3_fast(float x){
#if __has_builtin(__builtin_amdgcn_cvt_pk_fp8_f32)
  int pk = __builtin_amdgcn_cvt_pk_fp8_f32(x, x, 0, false);
  return (unsigned char)(pk & 0xff);
#else
  return enc_e4m3(x);
#endif
}

// ---------- K0: fp32 -> f16 convert (8 elems/thread) ----------
__global__ void k_cvt(const float* __restrict__ src, f16* __restrict__ dst, int n){
  int i = (blockIdx.x*256 + threadIdx.x)*8;
  if (i >= n) return;
  float4 a = *(const float4*)(src + i);
  float4 b = *(const float4*)(src + i + 4);
  f16x8 o;
  o[0]=(f16)a.x; o[1]=(f16)a.y; o[2]=(f16)a.z; o[3]=(f16)a.w;
  o[4]=(f16)b.x; o[5]=(f16)b.y; o[6]=(f16)b.z; o[7]=(f16)b.w;
  *(f16x8*)(dst+i) = o;
}

// ---------- K0c: pack W_hh into fp8 MFMA A-fragments ----------
// Entry idx = dir*32768 + wv*4096 + rt*512 + kt*64 + lane (one 8-byte frag each).
// Lane holds A[row][k] for row = lane&15, k = kt*32 + (lane>>4)*8 + j.
// Output row n = wv*128 + rt*16 + (lane&15). Weights prescaled by 16 into e4m3.
__global__ void k_wpack5(const float* __restrict__ whf, const float* __restrict__ whb,
                         unsigned int* __restrict__ wf){
  int idx = blockIdx.x*256 + threadIdx.x;    // 0..65535
  int lane = idx & 63;
  int kt   = (idx >> 6) & 7;
  int rt   = (idx >> 9) & 7;
  int wv   = (idx >> 12) & 7;
  int dir  = (idx >> 15) & 1;
  const float* w = dir ? whb : whf;
  int n  = wv*128 + rt*16 + (lane & 15);
  int k0 = kt*32 + (lane >> 4)*8;
  const float* row = w + (size_t)n*256 + k0;
  unsigned char by[8];
  #pragma unroll
  for (int j=0;j<8;j++) by[j] = enc_e4m3(row[j] * 16.0f);
  unsigned lo = (unsigned)by[0] | ((unsigned)by[1]<<8) | ((unsigned)by[2]<<16) | ((unsigned)by[3]<<24);
  unsigned hi = (unsigned)by[4] | ((unsigned)by[5]<<8) | ((unsigned)by[6]<<16) | ((unsigned)by[7]<<24);
  wf[(size_t)idx*2]   = lo;
  wf[(size_t)idx*2+1] = hi;
}

// ---------- K1: gx = X(32768x768) @ Wcat(2048x768)^T  (f16 out, fp32 acc MFMA) ----------
__global__ __launch_bounds__(256) void k_gemm(const f16* __restrict__ A,
                                              const f16* __restrict__ Bw,
                                              f16* __restrict__ C){
  __shared__ alignas(16) f16 As[128][64];
  __shared__ alignas(16) f16 Bs[128][64];
  int bid = blockIdx.x;
  int bm = bid >> 4, bn = bid & 15;
  int tid = threadIdx.x;
  int w = tid >> 6, l = tid & 63;
  int wm = w >> 1, wn = w & 1;
  f32x4 acc[4][4] = {};
  int srow = tid >> 3;
  int scol = (tid & 7)*8;
  const f16* Ag = A  + (size_t)(bm*128)*768 + scol;
  const f16* Bg = Bw + (size_t)(bn*128)*768 + scol;
  int fr = l & 15, kg = l >> 4;
  for (int k0 = 0; k0 < 768; k0 += 64){
    #pragma unroll
    for (int q=0;q<4;q++){
      int rr = srow + 32*q;
      u32x4 av = *(const u32x4*)(Ag + rr*768 + k0);
      u32x4 bv = *(const u32x4*)(Bg + rr*768 + k0);
      *(u32x4*)&As[rr][scol] = av;
      *(u32x4*)&Bs[rr][scol] = bv;
    }
    __syncthreads();
    #pragma unroll
    for (int ks=0; ks<2; ks++){
      f16x8 af[4], bf[4];
      #pragma unroll
      for (int mi=0;mi<4;mi++) af[mi] = *(const f16x8*)&As[wm*64+mi*16+fr][ks*32+kg*8];
      #pragma unroll
      for (int ni=0;ni<4;ni++) bf[ni] = *(const f16x8*)&Bs[wn*64+ni*16+fr][ks*32+kg*8];
      #pragma unroll
      for (int mi=0;mi<4;mi++)
        #pragma unroll
        for (int ni=0;ni<4;ni++)
          acc[mi][ni] = __builtin_amdgcn_mfma_f32_16x16x32_f16(af[mi], bf[ni], acc[mi][ni], 0,0,0);
    }
    __syncthreads();
  }
  int fq = l >> 4;
  #pragma unroll
  for (int mi=0;mi<4;mi++)
    #pragma unroll
    for (int ni=0;ni<4;ni++){
      int mrow = bm*128 + wm*64 + mi*16 + fq*4;
      int ncol = bn*128 + wn*64 + ni*16 + fr;
      #pragma unroll
      for (int r=0;r<4;r++)
        C[(size_t)(mrow+r)*2048 + ncol] = (f16)acc[mi][ni][r];
    }
}

// ---------- K2: recurrence via fp8 MFMA. One block per chain; 512 thr = 8 waves ----------
// Wave wv owns gate-output rows [wv*128, wv*128+128). A stationary in regs.
// B = h (e4m3) replicated into 16 cols from a 256B LDS buffer. Combine phase on
// tid<256. Both in-loop barriers are lgkmcnt-only so the gx prefetch stays in
// flight across the step boundary.
__global__ __launch_bounds__(512,2) void k_rnn(const unsigned int* __restrict__ wfrag,
            const f16* __restrict__ gx, const float* __restrict__ bfp,
            const float* __restrict__ bbp, f16* __restrict__ Hc){
  __shared__ alignas(16) float pacc[1024];
  __shared__ alignas(8) unsigned char lh8[2][256];
  int chain = blockIdx.x;
  int b = chain >> 1, dir = chain & 1;
  int tid = threadIdx.x;
  int wv = tid >> 6, lane = tid & 63;
  int klo = (lane >> 4) * 8;
  int u = tid & 255;
  const long* wf = (const long*)wfrag + (size_t)(dir*8 + wv)*4096 + lane;
  long a[64];                                   // a[rt*8+kt]
  #pragma unroll
  for (int i=0;i<64;i++) a[i] = wf[(size_t)i*64];
  const float* bias = dir ? bbp : bfp;
  const f16* gxc = gx + (size_t)(b*512)*2048;
  f16* Hcc = Hc + (size_t)(b*512)*512 + dir*256 + u;
  float bia0=0.f,bia1=0.f,bia2=0.f,bia3=0.f, c=0.f;
  f16 gn0=(f16)0.f, gn1=(f16)0.f, gn2=(f16)0.f, gn3=(f16)0.f;
  if (tid < 256){
    bia0 = bias[u]; bia1 = bias[256+u]; bia2 = bias[512+u]; bia3 = bias[768+u];
    lh8[0][u] = 0;
    int s0 = dir ? 511 : 0;
    const f16* gp = gxc + (size_t)s0*2048 + dir*1024 + u;
    gn0 = gp[0]; gn1 = gp[256]; gn2 = gp[512]; gn3 = gp[768];
  }
  __syncthreads();
  for (int t=0; t<512; t++){
    int cur = t & 1;
    f32x4 ac0={0,0,0,0},ac1={0,0,0,0},ac2={0,0,0,0},ac3={0,0,0,0};
    f32x4 ac4={0,0,0,0},ac5={0,0,0,0},ac6={0,0,0,0},ac7={0,0,0,0};
    #pragma unroll
    for (int kt=0; kt<8; kt++){
      long hb = *(const long*)&lh8[cur][kt*32 + klo];
      ac0 = __builtin_amdgcn_mfma_f32_16x16x32_fp8_fp8(a[0*8+kt], hb, ac0, 0,0,0);
      ac1 = __builtin_amdgcn_mfma_f32_16x16x32_fp8_fp8(a[1*8+kt], hb, ac1, 0,0,0);
      ac2 = __builtin_amdgcn_mfma_f32_16x16x32_fp8_fp8(a[2*8+kt], hb, ac2, 0,0,0);
      ac3 = __builtin_amdgcn_mfma_f32_16x16x32_fp8_fp8(a[3*8+kt], hb, ac3, 0,0,0);
      ac4 = __builtin_amdgcn_mfma_f32_16x16x32_fp8_fp8(a[4*8+kt], hb, ac4, 0,0,0);
      ac5 = __builtin_amdgcn_mfma_f32_16x16x32_fp8_fp8(a[5*8+kt], hb, ac5, 0,0,0);
      ac6 = __builtin_amdgcn_mfma_f32_16x16x32_fp8_fp8(a[6*8+kt], hb, ac6, 0,0,0);
      ac7 = __builtin_amdgcn_mfma_f32_16x16x32_fp8_fp8(a[7*8+kt], hb, ac7, 0,0,0);
    }
    if ((lane & 15) == 0){
      int pb = wv*128 + (lane >> 4)*4;          // row within tile = (lane>>4)*4 + reg
      *(f32x4*)&pacc[pb +   0] = ac0;
      *(f32x4*)&pacc[pb +  16] = ac1;
      *(f32x4*)&pacc[pb +  32] = ac2;
      *(f32x4*)&pacc[pb +  48] = ac3;
      *(f32x4*)&pacc[pb +  64] = ac4;
      *(f32x4*)&pacc[pb +  80] = ac5;
      *(f32x4*)&pacc[pb +  96] = ac6;
      *(f32x4*)&pacc[pb + 112] = ac7;
    }
    bar_lgkm();
    if (tid < 256){
      int s = dir ? (511-t) : t;
      // issue next step's gx prefetch FIRST (stays in flight across barrier)
      int tn = (t < 511) ? t+1 : 511;
      int sn = dir ? (511 - tn) : tn;
      const f16* gp = gxc + (size_t)sn*2048 + dir*1024 + u;
      f16 f0 = gp[0], f1 = gp[256], f2 = gp[512], f3 = gp[768];
      float p0 = pacc[      u]*0.0625f + bia0 + (float)gn0;
      float p1 = pacc[256 + u]*0.0625f + bia1 + (float)gn1;
      float p2 = pacc[512 + u]*0.0625f + bia2 + (float)gn2;
      float p3 = pacc[768 + u]*0.0625f + bia3 + (float)gn3;
      float ig = sigm(p0), fg = sigm(p1);
      float gg = tanh_(p2), og = sigm(p3);
      c = fg*c + ig*gg;
      float h = og*tanh_(c);
      Hcc[(size_t)s*512] = (f16)h;
      lh8[cur^1][u] = enc_e4m3_fast(h);
      gn0 = f0; gn1 = f1; gn2 = f2; gn3 = f3;
    }
    bar_lgkm();
  }
}

// ---------- K3: emissions e[m][k] = Hcat[m] . Wproj[k] + b_proj[k]  (wave per row) ----------
__global__ __launch_bounds__(256) void k_emis(const f16* __restrict__ Hc,
                 const f16* __restrict__ Wp, const float* __restrict__ bp,
                 float* __restrict__ e){
  int w = threadIdx.x >> 6, l = threadIdx.x & 63;
  int m = blockIdx.x*4 + w;
  f16x8 hv = *(const f16x8*)(Hc + (size_t)m*512 + l*8);
  u32x4 hu = __builtin_bit_cast(u32x4, hv);
  #pragma unroll
  for (int k=0;k<9;k++){
    f16x8 wv = *(const f16x8*)(Wp + k*512 + l*8);
    u32x4 wu = __builtin_bit_cast(u32x4, wv);
    float p = 0.f;
    #pragma unroll
    for (int q=0;q<4;q++) p = dot2u(hu[q], wu[q], p);
    #pragma unroll
    for (int off=32; off; off>>=1) p += __shfl_xor(p, off);
    if (l == k) e[(size_t)m*9 + k] = p + bp[k];
  }
}

// ---------- K4: CRF negative-llh pieces per batch (1 wave per batch) ----------
__global__ void k_crf(const float* __restrict__ e, const int* __restrict__ tags,
                      const int* __restrict__ mask, const float* __restrict__ st,
                      const float* __restrict__ en, const float* __restrict__ tr,
                      float* __restrict__ llh){
  int b = blockIdx.x;
  int l = threadIdx.x;
  int j = (l < 9) ? l : 0;
  float Tc[9];
  #pragma unroll
  for (int i=0;i<9;i++) Tc[i] = tr[i*9 + j];
  const float* eb = e + (size_t)b*512*9;
  const int* tb = tags + b*512;
  const int* mb = mask + b*512;
  float a = st[j] + eb[j];
  int t0 = tb[0];
  float num = st[t0] + eb[t0];
  int prev = t0;
  int cnt = (mb[0] != 0) ? 1 : 0;
  for (int s=1; s<512; s++){
    float ej = eb[s*9 + j];
    float vi[9];
    #pragma unroll
    for (int i=0;i<9;i++) vi[i] = __shfl(a, i) + Tc[i];
    float mx = vi[0];
    #pragma unroll
    for (int i=1;i<9;i++) mx = fmaxf(mx, vi[i]);
    float ssum = 0.f;
    #pragma unroll
    for (int i=0;i<9;i++) ssum += expf(vi[i]-mx);
    float anew = ej + mx + logf(ssum);
    int mt = mb[s];
    a = (mt != 0) ? anew : a;
    int tg = tb[s];
    num += (float)mt * (tr[prev*9+tg] + eb[s*9+tg]);
    prev = tg;
    cnt += (mt != 0) ? 1 : 0;
  }
  float av[9];
  #pragma unroll
  for (int i=0;i<9;i++) av[i] = __shfl(a, i) + en[i];
  float mx = av[0];
  #pragma unroll
  for (int i=1;i<9;i++) mx = fmaxf(mx, av[i]);
  float ssum = 0.f;
  #pragma unroll
  for (int i=0;i<9;i++) ssum += expf(av[i]-mx);
  float logZ = mx + logf(ssum);
  if (l == 0){
    int lastt = tb[cnt-1];
    llh[b] = (num + en[lastt]) - logZ;
  }
}

// ---------- K5: final reduce ----------
__global__ void k_red(const float* __restrict__ llh, float* __restrict__ out){
  if (threadIdx.x == 0){
    float s = 0.f;
    for (int i=0;i<64;i++) s += llh[i];
    out[0] = -s / 64.0f;
  }
}

extern "C" void kernel_launch(void* const* d_in, const int* in_sizes, int n_in,
                              void* d_out, int out_size, void* d_ws, size_t ws_size,
                              hipStream_t stream){
  const float* emb  = (const float*)d_in[0];
  const int*   tags = (const int*)d_in[1];
  const int*   mask = (const int*)d_in[2];
  const float* wihf = (const float*)d_in[3];
  const float* whhf = (const float*)d_in[4];
  const float* bfp  = (const float*)d_in[5];
  const float* wihb = (const float*)d_in[6];
  const float* whhb = (const float*)d_in[7];
  const float* bbp  = (const float*)d_in[8];
  const float* wprj = (const float*)d_in[9];
  const float* bprj = (const float*)d_in[10];
  const float* st   = (const float*)d_in[11];
  const float* en   = (const float*)d_in[12];
  const float* tr   = (const float*)d_in[13];

  char* ws = (char*)d_ws;
  f16*   Xf    = (f16*)(ws + 0);                 // 50,331,648 B (aliased by Hc later)
  f16*   Wcat  = (f16*)(ws + 50331648);          //  3,145,728 B
  unsigned int* Wpack = (unsigned int*)(ws + 53477376);  // 524,288 B used (1 MB slot)
  f16*   Wpj   = (f16*)(ws + 54525952);          //      9,216 B
  f16*   gx    = (f16*)(ws + 54535168);          // 134,217,728 B
  float* e     = (float*)(ws + 188752896);       //  1,179,648 B
  float* llh   = (float*)(ws + 189932544);       //        256 B
  f16*   Hc    = Xf;   // safe alias: X only read by k_gemm, which precedes k_rnn

  hipLaunchKernelGGL(k_cvt,    dim3(12288), dim3(256), 0, stream, emb,  Xf, 25165824);
  hipLaunchKernelGGL(k_cvt,    dim3(384),   dim3(256), 0, stream, wihf, Wcat,          786432);
  hipLaunchKernelGGL(k_cvt,    dim3(384),   dim3(256), 0, stream, wihb, Wcat + 786432, 786432);
  hipLaunchKernelGGL(k_cvt,    dim3(3),     dim3(256), 0, stream, wprj, Wpj, 4608);
  hipLaunchKernelGGL(k_wpack5, dim3(256),   dim3(256), 0, stream, whhf, whhb, Wpack);
  hipLaunchKernelGGL(k_gemm,   dim3(4096),  dim3(256), 0, stream, Xf, Wcat, gx);
  hipLaunchKernelGGL(k_rnn,    dim3(128),   dim3(512), 0, stream, Wpack, gx, bfp, bbp, Hc);
  hipLaunchKernelGGL(k_emis,   dim3(8192),  dim3(256), 0, stream, Hc, Wpj, bprj, e);
  hipLaunchKernelGGL(k_crf,    dim3(64),    dim3(64),  0, stream, e, tags, mask, st, en, tr, llh);
  hipLaunchKernelGGL(k_red,    dim3(1),     dim3(64),  0, stream, llh, (float*)d_out);
}